// Round 4
// baseline (898.827 us; speedup 1.0000x reference)
//
#include <hip/hip_runtime.h>
#include <hip/hip_bf16.h>

#define NN 1048576
#define NG 16384
#define DD 128
#define GRID 2048

typedef __bf16 bf16x8 __attribute__((ext_vector_type(8)));
typedef float f32x4 __attribute__((ext_vector_type(4)));
typedef unsigned short us8v __attribute__((ext_vector_type(8)));

__device__ __forceinline__ unsigned short f2bf(float f) {
    unsigned int u = __float_as_uint(f);
    u += 0x7FFFu + ((u >> 16) & 1u);
    return (unsigned short)(u >> 16);
}

__global__ void prep_kernel(const int* __restrict__ gid, const float* __restrict__ W,
                            int* __restrict__ starts, unsigned short* __restrict__ Wl) {
    int t = blockIdx.x * 256 + threadIdx.x;
    if (t <= NG) {
        int lo = 0, hi = NN;
        while (lo < hi) { int mid = (lo + hi) >> 1; if (gid[mid] < t) lo = mid + 1; else hi = mid; }
        starts[t] = lo;
    }
    if (t < DD * DD) {
        // fragment-ordered B layout: Wl[((n*4+kk)*64 + l)*8 + e] = bf16(W[k][col]),
        // k = kk*32 + (l>>4)*8 + e, col = n*16 + (l&15)
        int e = t & 7, l = (t >> 3) & 63, kk = (t >> 9) & 3, n = t >> 11;
        int k = kk * 32 + (l >> 4) * 8 + e;
        int col = n * 16 + (l & 15);
        Wl[t] = f2bf(W[k * DD + col]);
    }
}

// Block-per-graph (grid-stride). 4 waves x 16 rows per 64-row window, each wave
// keeps an INDEPENDENT online-softmax state (no chunk-loop barriers); states are
// merged once per graph via 6KB LDS scratch (online softmax is associative).
__global__ __launch_bounds__(256, 3) void fused_kernel(
    const float* __restrict__ x, const int* __restrict__ starts,
    const unsigned short* __restrict__ Wl,
    const float* __restrict__ b_enc, const float* __restrict__ w_q1,
    const float* __restrict__ b_q1, const float* __restrict__ w_q2,
    const float* __restrict__ b_q2, float* __restrict__ out) {

    __shared__ unsigned short Wl_lds[DD * DD];   // 32 KB fragment-ordered, lane-linear
    __shared__ float scr[4][3][DD];              // per-wave merge scratch
    __shared__ float mzs[4][4];                  // per-wave m1,z1,m2,z2
    __shared__ float bv[DD], w1v[DD], w2v[DD];

    const int t = threadIdx.x, w = t >> 6, l = t & 63;
    const int lr = l & 15, lk = l >> 4;

    for (int i = t; i < (DD * DD) / 8; i += 256)
        *(us8v*)&Wl_lds[i * 8] = *(const us8v*)&Wl[i * 8];
    if (t < DD) { bv[t] = b_enc[t]; w1v[t] = w_q1[t]; w2v[t] = w_q2[t]; }
    const float bq1 = b_q1[0], bq2 = b_q2[0];
    __syncthreads();

    int g = blockIdx.x;
    int seg0 = starts[g], seg1 = starts[g + 1];

    float4 pf[8];
    auto issue = [&](int row0, int hi) {   // rows (row0+lr) clamped to hi-1; unconditional
        const int grow = min(row0 + lr, hi - 1);
        const float* xp = x + (size_t)grow * DD + lk * 8;
#pragma unroll
        for (int kk = 0; kk < 4; ++kk) {
            pf[2 * kk]     = *(const float4*)(xp + kk * 32);
            pf[2 * kk + 1] = *(const float4*)(xp + kk * 32 + 4);
        }
    };
    if (seg0 < seg1) issue(seg0 + w * 16, seg1);

    float m1 = -1e30f, m2 = -1e30f, z1 = 0.f, z2 = 0.f;
    float ka[8], q1a[8], q2a[8];
#pragma unroll
    for (int n = 0; n < 8; ++n) { ka[n] = 0.f; q1a[n] = 0.f; q2a[n] = 0.f; }

    while (true) {
        const int cnt = seg1 - seg0;
        const int gn = g + GRID;
        int c0 = seg0 + w * 16;

        if (c0 >= seg1) {
            // this wave has no rows in g: keep the prefetch chain alive
            if (gn < NG) {
                const int ns0 = starts[gn], ns1 = starts[gn + 1];
                if (ns0 < ns1) issue(ns0 + w * 16, ns1);
            }
        } else {
            for (; c0 < seg1; c0 += 64) {
                // ---- consume prefetch: fp32 -> bf16 A-fragments ----
                bf16x8 afr[4];
#pragma unroll
                for (int kk = 0; kk < 4; ++kk) {
                    float4 a = pf[2 * kk], b2 = pf[2 * kk + 1];
                    us8v uv;
                    uv[0] = f2bf(a.x); uv[1] = f2bf(a.y); uv[2] = f2bf(a.z); uv[3] = f2bf(a.w);
                    uv[4] = f2bf(b2.x); uv[5] = f2bf(b2.y); uv[6] = f2bf(b2.z); uv[7] = f2bf(b2.w);
                    afr[kk] = __builtin_bit_cast(bf16x8, uv);
                }
                // ---- issue next prefetch (same graph, else next graph's wave-slice) ----
                if (c0 + 64 < seg1) issue(c0 + 64, seg1);
                else if (gn < NG) {
                    const int ns0 = starts[gn], ns1 = starts[gn + 1];
                    if (ns0 < ns1) issue(ns0 + w * 16, ns1);
                }

                // ---- MFMA: h[16 x 128] ----
                f32x4 acc[8];
#pragma unroll
                for (int n = 0; n < 8; ++n) { acc[n][0] = 0.f; acc[n][1] = 0.f; acc[n][2] = 0.f; acc[n][3] = 0.f; }
#pragma unroll
                for (int n = 0; n < 8; ++n)
#pragma unroll
                    for (int kk = 0; kk < 4; ++kk) {
                        bf16x8 bfr = *(const bf16x8*)&Wl_lds[((n * 4 + kk) * 64 + l) * 8];
                        acc[n] = __builtin_amdgcn_mfma_f32_16x16x32_bf16(afr[kk], bfr, acc[n], 0, 0, 0);
                    }

                // ---- bias+relu, score partials (C: col=n*16+lr, row=lk*4+j) ----
                float p1[4] = {0.f, 0.f, 0.f, 0.f}, p2[4] = {0.f, 0.f, 0.f, 0.f};
#pragma unroll
                for (int n = 0; n < 8; ++n) {
                    const float bb = bv[n * 16 + lr];
                    const float w1 = w1v[n * 16 + lr];
                    const float w2 = w2v[n * 16 + lr];
#pragma unroll
                    for (int j = 0; j < 4; ++j) {
                        float hv = fmaxf(acc[n][j] + bb, 0.f);
                        acc[n][j] = hv;
                        p1[j] += hv * w1;
                        p2[j] += hv * w2;
                    }
                }
#pragma unroll
                for (int j = 0; j < 4; ++j)
#pragma unroll
                    for (int d = 1; d < 16; d <<= 1) {
                        p1[j] += __shfl_xor(p1[j], d);
                        p2[j] += __shfl_xor(p2[j], d);
                    }

                // ---- per-wave online softmax over its 16 rows ----
                float v1[4], v2[4];
                float r1 = -1e30f, r2 = -1e30f;
#pragma unroll
                for (int j = 0; j < 4; ++j) {
                    const bool v = (c0 + lk * 4 + j) < seg1;
                    v1[j] = v ? p1[j] + bq1 : -1e30f;
                    v2[j] = v ? p2[j] + bq2 : -1e30f;
                    r1 = fmaxf(r1, v1[j]); r2 = fmaxf(r2, v2[j]);
                }
                r1 = fmaxf(r1, __shfl_xor(r1, 16)); r1 = fmaxf(r1, __shfl_xor(r1, 32));
                r2 = fmaxf(r2, __shfl_xor(r2, 16)); r2 = fmaxf(r2, __shfl_xor(r2, 32));

                const float nm1 = fmaxf(m1, r1), nm2 = fmaxf(m2, r2);
                const float sc1 = __expf(m1 - nm1), sc2 = __expf(m2 - nm2);
                float e1j[4], e2j[4];
                float cz1 = 0.f, cz2 = 0.f;
#pragma unroll
                for (int j = 0; j < 4; ++j) {
                    e1j[j] = __expf(v1[j] - nm1);
                    e2j[j] = __expf(v2[j] - nm2);
                    cz1 += e1j[j]; cz2 += e2j[j];
                }
                cz1 += __shfl_xor(cz1, 16); cz1 += __shfl_xor(cz1, 32);
                cz2 += __shfl_xor(cz2, 16); cz2 += __shfl_xor(cz2, 32);
                z1 = z1 * sc1 + cz1; z2 = z2 * sc2 + cz2;
                m1 = nm1; m2 = nm2;

#pragma unroll
                for (int n = 0; n < 8; ++n) {
                    float kaa = 0.f, q1aa = 0.f, q2aa = 0.f;
#pragma unroll
                    for (int j = 0; j < 4; ++j) {
                        const float hv = acc[n][j];
                        const bool v = (c0 + lk * 4 + j) < seg1;
                        kaa  += v ? hv : 0.f;
                        q1aa += e1j[j] * hv;
                        q2aa += e2j[j] * hv;
                    }
                    ka[n] += kaa;
                    q1a[n] = q1a[n] * sc1 + q1aa;
                    q2a[n] = q2a[n] * sc2 + q2aa;
                }
            }
        }

        // ---- per-graph merge of 4 independent wave states ----
#pragma unroll
        for (int n = 0; n < 8; ++n)
#pragma unroll
            for (int d = 16; d < 64; d <<= 1) {
                ka[n]  += __shfl_xor(ka[n],  d);
                q1a[n] += __shfl_xor(q1a[n], d);
                q2a[n] += __shfl_xor(q2a[n], d);
            }
        __syncthreads();   // prev graph's merge readers done
        if (lk == 0) {
#pragma unroll
            for (int n = 0; n < 8; ++n) {
                scr[w][0][n * 16 + lr] = ka[n];
                scr[w][1][n * 16 + lr] = q1a[n];
                scr[w][2][n * 16 + lr] = q2a[n];
            }
            if (lr == 0) { mzs[w][0] = m1; mzs[w][1] = z1; mzs[w][2] = m2; mzs[w][3] = z2; }
        }
        __syncthreads();
        if (t < DD) {
            float M1 = mzs[0][0], M2 = mzs[0][2];
#pragma unroll
            for (int wv = 1; wv < 4; ++wv) {
                M1 = fmaxf(M1, mzs[wv][0]);
                M2 = fmaxf(M2, mzs[wv][2]);
            }
            float Z1 = 0.f, Z2 = 0.f, KT = 0.f, Q1 = 0.f, Q2 = 0.f;
#pragma unroll
            for (int wv = 0; wv < 4; ++wv) {
                const float e1 = __expf(mzs[wv][0] - M1);
                const float e2 = __expf(mzs[wv][2] - M2);
                Z1 += mzs[wv][1] * e1;
                Z2 += mzs[wv][3] * e2;
                KT += scr[wv][0][t];
                Q1 += scr[wv][1][t] * e1;
                Q2 += scr[wv][2][t] * e2;
            }
            out[(size_t)g * DD + t]            = KT / fmaxf((float)cnt, 1.f);
            out[(size_t)(NG + g) * DD + t]     = Q1 / fmaxf(Z1, 1e-12f);
            out[(size_t)(2 * NG + g) * DD + t] = Q2 / fmaxf(Z2, 1e-12f);
        }

        if (gn >= NG) return;
        g = gn; seg0 = starts[g]; seg1 = starts[g + 1];
        m1 = -1e30f; m2 = -1e30f; z1 = 0.f; z2 = 0.f;
#pragma unroll
        for (int n = 0; n < 8; ++n) { ka[n] = 0.f; q1a[n] = 0.f; q2a[n] = 0.f; }
    }
}

extern "C" void kernel_launch(void* const* d_in, const int* in_sizes, int n_in,
                              void* d_out, int out_size, void* d_ws, size_t ws_size,
                              hipStream_t stream) {
    const float* x     = (const float*)d_in[0];
    const int*   gid   = (const int*)d_in[1];
    const float* W     = (const float*)d_in[2];
    const float* b_enc = (const float*)d_in[3];
    const float* w_q1  = (const float*)d_in[4];
    const float* b_q1  = (const float*)d_in[5];
    const float* w_q2  = (const float*)d_in[6];
    const float* b_q2  = (const float*)d_in[7];
    float* out = (float*)d_out;

    int* starts        = (int*)d_ws;                                // (NG+1) ints
    unsigned short* Wl = (unsigned short*)((char*)d_ws + 131072);   // 128*128 bf16, fragment-ordered

    prep_kernel<<<65, 256, 0, stream>>>(gid, W, starts, Wl);
    fused_kernel<<<GRID, 256, 0, stream>>>(x, starts, Wl, b_enc, w_q1, b_q1, w_q2, b_q2, out);
}

// Round 5
// 190.474 us; speedup vs baseline: 4.7189x; 4.7189x over previous
//
#include <hip/hip_runtime.h>
#include <hip/hip_bf16.h>

#define NN 1048576
#define NG 16384
#define DD 128
#define GRIDB 512
#define WSTRIDE (GRIDB * 4)   // 2048 waves, 8 graphs per wave

typedef __bf16 bf16x8 __attribute__((ext_vector_type(8)));
typedef float f32x4 __attribute__((ext_vector_type(4)));

#define WAIT_VM8()  asm volatile("s_waitcnt vmcnt(8)" ::: "memory")
#define WAIT_VM0()  asm volatile("s_waitcnt vmcnt(0)" ::: "memory")
#define WAIT_LGKM() asm volatile("s_waitcnt lgkmcnt(0)" ::: "memory")

__device__ __forceinline__ unsigned short f2bf(float f) {
    unsigned int u = __float_as_uint(f);
    u += 0x7FFFu + ((u >> 16) & 1u);
    return (unsigned short)(u >> 16);
}

__global__ void prep_kernel(const int* __restrict__ gid, const float* __restrict__ W,
                            int* __restrict__ starts, unsigned short* __restrict__ Wl) {
    int t = blockIdx.x * 256 + threadIdx.x;
    if (t <= NG) {
        int lo = 0, hi = NN;
        while (lo < hi) { int mid = (lo + hi) >> 1; if (gid[mid] < t) lo = mid + 1; else hi = mid; }
        starts[t] = lo;
    }
    if (t < DD * DD) {
        // fragment-ordered B: Wl[((n*4+kk)*64 + l)*8 + e] = bf16(W[k][col]),
        // k = kk*32 + (l>>4)*8 + e, col = n*16 + (l&15)
        int e = t & 7, l = (t >> 3) & 63, kk = (t >> 9) & 3, n = t >> 11;
        int k = kk * 32 + (l >> 4) * 8 + e;
        int col = n * 16 + (l & 15);
        Wl[t] = f2bf(W[k * DD + col]);
    }
}

// Wave-per-graph. x prefetched via async global_load_lds into a per-wave
// 2-buffer LDS ring (counted vmcnt, never drained in steady state). W held in
// 128 loop-invariant VGPRs. No barriers in the main loop.
__global__ __launch_bounds__(256, 2) void fused_kernel(
    const float* __restrict__ x, const int* __restrict__ starts,
    const unsigned short* __restrict__ Wl,
    const float* __restrict__ b_enc, const float* __restrict__ w_q1,
    const float* __restrict__ b_q1, const float* __restrict__ w_q2,
    const float* __restrict__ b_q2, float* __restrict__ out) {

    __shared__ float xbuf[4][2][16 * 128];   // 64 KB: wave x buf x (16 rows * 512B)
    __shared__ float bwq[DD][4];             // {b_enc, w_q1, w_q2, 0} per col

    const int t = threadIdx.x, w = t >> 6, l = t & 63;
    const int lr = l & 15, lk = l >> 4;

    if (t < DD) { bwq[t][0] = b_enc[t]; bwq[t][1] = w_q1[t]; bwq[t][2] = w_q2[t]; bwq[t][3] = 0.f; }

    // W fragments -> registers (loop-invariant, 128 VGPRs)
    bf16x8 wfr[8][4];
#pragma unroll
    for (int n = 0; n < 8; ++n)
#pragma unroll
        for (int kk = 0; kk < 4; ++kk)
            wfr[n][kk] = *(const bf16x8*)&Wl[((n * 4 + kk) * 64 + l) * 8];

    const float bq1 = b_q1[0], bq2 = b_q2[0];
    __syncthreads();   // bwq ready; last barrier in the kernel

    const int g0 = blockIdx.x * 4 + w;

    // ---- issue cursor (wave-uniform), skips empty graphs ----
    int ig = g0, ic0 = 0, is1 = 0;
    {
        ic0 = starts[ig]; is1 = starts[ig + 1];
        while (ic0 >= is1) {
            ig += WSTRIDE;
            if (ig >= NG) break;
            ic0 = starts[ig]; is1 = starts[ig + 1];
        }
    }

    auto issue_tile = [&](int bufIdx) {
        const int hi = is1 - 1;
#pragma unroll
        for (int inst = 0; inst < 8; ++inst) {
            const int rit = inst * 2 + (l >> 5);            // row in tile 0..15
            const int grow = min(ic0 + rit, hi);            // clamped global row
            const int su = (l & 31) ^ (rit & 7);            // swizzled 16B unit
            const float* src = x + (size_t)grow * DD + su * 4;
            float* dst = &xbuf[w][bufIdx][inst * 256];      // wave-uniform base
            __builtin_amdgcn_global_load_lds(
                (const __attribute__((address_space(1))) void*)src,
                (__attribute__((address_space(3))) void*)dst, 16, 0, 0);
        }
    };
    auto adv_issue = [&]() {
        ic0 += 16;
        while (ic0 >= is1) {
            ig += WSTRIDE;
            if (ig >= NG) break;
            ic0 = starts[ig]; is1 = starts[ig + 1];
        }
    };

    int inflight = 0;
    if (ig < NG) { issue_tile(0); adv_issue(); inflight = 1; }
    if (ig < NG) { issue_tile(1); adv_issue(); inflight = 2; }
    int buf = 0;

    for (int cg = g0; cg < NG; cg += WSTRIDE) {
        const int cs0 = starts[cg], cs1 = starts[cg + 1];
        const int cnt = cs1 - cs0;

        float m1 = -1e30f, m2 = -1e30f, z1 = 0.f, z2 = 0.f;
        float ka[8], q1a[8], q2a[8];
#pragma unroll
        for (int n = 0; n < 8; ++n) { ka[n] = 0.f; q1a[n] = 0.f; q2a[n] = 0.f; }

        for (int cc0 = cs0; cc0 < cs1; cc0 += 16) {
            if (inflight >= 2) { WAIT_VM8(); } else { WAIT_VM0(); }

            // ---- read tile from LDS (swizzled), convert to bf16 A-frags ----
            const float* xb = &xbuf[w][buf][0];
            bf16x8 afr[4];
#pragma unroll
            for (int kk = 0; kk < 4; ++kk) {
                const int u0 = (kk * 8 + lk * 2)     ^ (lr & 7);
                const int u1 = (kk * 8 + lk * 2 + 1) ^ (lr & 7);
                const float4 f0 = *(const float4*)&xb[lr * 128 + u0 * 4];
                const float4 f1 = *(const float4*)&xb[lr * 128 + u1 * 4];
                bf16x8 a;
                a[0] = (__bf16)f0.x; a[1] = (__bf16)f0.y; a[2] = (__bf16)f0.z; a[3] = (__bf16)f0.w;
                a[4] = (__bf16)f1.x; a[5] = (__bf16)f1.y; a[6] = (__bf16)f1.z; a[7] = (__bf16)f1.w;
                afr[kk] = a;
            }
            WAIT_LGKM();                       // done reading buf
            inflight--;
            if (ig < NG) { issue_tile(buf); adv_issue(); inflight++; }
            buf ^= 1;

            // ---- MFMA: h[16 x 128] (A from DMA tile, B from regs) ----
            f32x4 acc[8];
#pragma unroll
            for (int n = 0; n < 8; ++n) { acc[n][0] = 0.f; acc[n][1] = 0.f; acc[n][2] = 0.f; acc[n][3] = 0.f; }
#pragma unroll
            for (int n = 0; n < 8; ++n)
#pragma unroll
                for (int kk = 0; kk < 4; ++kk)
                    acc[n] = __builtin_amdgcn_mfma_f32_16x16x32_bf16(afr[kk], wfr[n][kk], acc[n], 0, 0, 0);

            // ---- bias+relu, score partials (C: col=n*16+lr, row=lk*4+j) ----
            float p1[4] = {0.f, 0.f, 0.f, 0.f}, p2[4] = {0.f, 0.f, 0.f, 0.f};
#pragma unroll
            for (int n = 0; n < 8; ++n) {
                const float4 bw = *(const float4*)bwq[n * 16 + lr];
#pragma unroll
                for (int j = 0; j < 4; ++j) {
                    float hv = fmaxf(acc[n][j] + bw.x, 0.f);
                    acc[n][j] = hv;
                    p1[j] += hv * bw.y;
                    p2[j] += hv * bw.z;
                }
            }
#pragma unroll
            for (int j = 0; j < 4; ++j)
#pragma unroll
                for (int d = 1; d < 16; d <<= 1) {
                    p1[j] += __shfl_xor(p1[j], d);
                    p2[j] += __shfl_xor(p2[j], d);
                }

            // ---- per-wave online softmax over 16 rows ----
            float v1[4], v2[4];
            float r1 = -1e30f, r2 = -1e30f;
#pragma unroll
            for (int j = 0; j < 4; ++j) {
                const bool vv = (cc0 + lk * 4 + j) < cs1;
                v1[j] = vv ? p1[j] + bq1 : -1e30f;
                v2[j] = vv ? p2[j] + bq2 : -1e30f;
                r1 = fmaxf(r1, v1[j]); r2 = fmaxf(r2, v2[j]);
            }
            r1 = fmaxf(r1, __shfl_xor(r1, 16)); r1 = fmaxf(r1, __shfl_xor(r1, 32));
            r2 = fmaxf(r2, __shfl_xor(r2, 16)); r2 = fmaxf(r2, __shfl_xor(r2, 32));

            const float nm1 = fmaxf(m1, r1), nm2 = fmaxf(m2, r2);
            const float sc1 = __expf(m1 - nm1), sc2 = __expf(m2 - nm2);
            float e1j[4], e2j[4];
            float cz1 = 0.f, cz2 = 0.f;
#pragma unroll
            for (int j = 0; j < 4; ++j) {
                e1j[j] = __expf(v1[j] - nm1);
                e2j[j] = __expf(v2[j] - nm2);
                cz1 += e1j[j]; cz2 += e2j[j];
            }
            cz1 += __shfl_xor(cz1, 16); cz1 += __shfl_xor(cz1, 32);
            cz2 += __shfl_xor(cz2, 16); cz2 += __shfl_xor(cz2, 32);
            z1 = z1 * sc1 + cz1; z2 = z2 * sc2 + cz2;
            m1 = nm1; m2 = nm2;

#pragma unroll
            for (int n = 0; n < 8; ++n) {
                float kaa = 0.f, q1aa = 0.f, q2aa = 0.f;
#pragma unroll
                for (int j = 0; j < 4; ++j) {
                    const float hv = acc[n][j];
                    const bool vv = (cc0 + lk * 4 + j) < cs1;
                    kaa  += vv ? hv : 0.f;
                    q1aa += e1j[j] * hv;
                    q2aa += e2j[j] * hv;
                }
                ka[n] += kaa;
                q1a[n] = q1a[n] * sc1 + q1aa;
                q2a[n] = q2a[n] * sc2 + q2aa;
            }
        }

        // ---- writeout: reduce over lk (bits 4,5), 2 cols per lane ----
#pragma unroll
        for (int n = 0; n < 8; ++n)
#pragma unroll
            for (int d = 16; d < 64; d <<= 1) {
                ka[n]  += __shfl_xor(ka[n],  d);
                q1a[n] += __shfl_xor(q1a[n], d);
                q2a[n] += __shfl_xor(q2a[n], d);
            }
        const float inv_cnt = 1.f / fmaxf((float)cnt, 1.f);
        const float iz1 = 1.f / fmaxf(z1, 1e-12f);
        const float iz2 = 1.f / fmaxf(z2, 1e-12f);
#pragma unroll
        for (int n2 = 0; n2 < 2; ++n2) {
            const int n = lk * 2 + n2;
            const int col = n * 16 + lr;
            out[(size_t)cg * DD + col]            = ka[n]  * inv_cnt;
            out[(size_t)(NG + cg) * DD + col]     = q1a[n] * iz1;
            out[(size_t)(2 * NG + cg) * DD + col] = q2a[n] * iz2;
        }
    }
}

extern "C" void kernel_launch(void* const* d_in, const int* in_sizes, int n_in,
                              void* d_out, int out_size, void* d_ws, size_t ws_size,
                              hipStream_t stream) {
    const float* x     = (const float*)d_in[0];
    const int*   gid   = (const int*)d_in[1];
    const float* W     = (const float*)d_in[2];
    const float* b_enc = (const float*)d_in[3];
    const float* w_q1  = (const float*)d_in[4];
    const float* b_q1  = (const float*)d_in[5];
    const float* w_q2  = (const float*)d_in[6];
    const float* b_q2  = (const float*)d_in[7];
    float* out = (float*)d_out;

    int* starts        = (int*)d_ws;                                // (NG+1) ints
    unsigned short* Wl = (unsigned short*)((char*)d_ws + 131072);   // 128*128 bf16, fragment-ordered

    prep_kernel<<<65, 256, 0, stream>>>(gid, W, starts, Wl);
    fused_kernel<<<GRIDB, 256, 0, stream>>>(x, starts, Wl, b_enc, w_q1, b_q1, w_q2, b_q2, out);
}